// Round 16
// baseline (290.858 us; speedup 1.0000x reference)
//
#include <hip/hip_runtime.h>

#define N_NODES 100000
#define N_EDGES 1600000
#define N_GRAPHS 128
#define FDIM 64
#define EPSV 1e-5f
#define NEG 0.01f

#define NB 782              // ceil(N_NODES/128) dst-range buckets
#define PART_BLOCKS 391     // ceil(N_EDGES/4096)
#define CVT_BLOCKS 1563     // ceil(1.6M float4 / 1024 per block)
#define NTILES 6250         // N_NODES/16 (exact)
#define TPB 2               // tiles per gemm block
#define GEMM_BLOCKS 3125    // NTILES/TPB (exact)
#define BN_SLOTS 128        // low-contention BN scratch slots

typedef short bf16x8 __attribute__((ext_vector_type(8)));
typedef float f32x4  __attribute__((ext_vector_type(4)));

__device__ __forceinline__ float leaky(float x){ return x >= 0.f ? x : NEG*x; }

__device__ __forceinline__ unsigned short f2bf(float x){          // RN-even
    unsigned u = __float_as_uint(x);
    return (unsigned short)((u + 0x7fffu + ((u >> 16) & 1u)) >> 16);
}
__device__ __forceinline__ float bf2f(unsigned short b){
    return __uint_as_float(((unsigned)b) << 16);
}

// ===== W-fragment builder: per-lane MFMA B-operand frags, scale-folded, hi/lo split =====
// out blob layout: thread t (= jt*64+lane) owns 8 x bf16x8 at out + t*64 shorts:
//   [0]=wlh0 [1]=wlh1 [2]=wll0 [3]=wll1 [4]=wrh0 [5]=wrh1 [6]=wrl0 [7]=wrl1
__device__ __forceinline__ void build_wfrag(const float* __restrict__ Wl,
                                            const float* __restrict__ Wr,
                                            const float* scl,   // nullptr => 1.0
                                            int t, unsigned short* __restrict__ out){
    int lane = t & 63, jt = t >> 6;
    int g = lane >> 4, r = lane & 15;
    int j = (jt << 4) + r;
    bf16x8 fr[8];
    #pragma unroll
    for (int ks = 0; ks < 2; ++ks){
        #pragma unroll
        for (int i = 0; i < 8; ++i){
            int k = (ks << 5) + (g << 3) + i;
            float s = scl ? scl[k] : 1.f;
            float wv = Wl[(k << 6) + j] * s;
            unsigned u = __float_as_uint(wv);
            fr[0 + ks][i] = (short)(u >> 16);
            float lf = wv - __uint_as_float(u & 0xffff0000u);
            fr[2 + ks][i] = (short)(__float_as_uint(lf) >> 16);
            wv = Wr[(k << 6) + j] * s;
            u = __float_as_uint(wv);
            fr[4 + ks][i] = (short)(u >> 16);
            lf = wv - __uint_as_float(u & 0xffff0000u);
            fr[6 + ks][i] = (short)(__float_as_uint(lf) >> 16);
        }
    }
    bf16x8* op = (bf16x8*)(out + (size_t)t * 64);
    #pragma unroll
    for (int m = 0; m < 8; ++m) op[m] = fr[m];
}

// ===== merged: fp32->bf16 convert + bucket histogram + zero scratch + layer-1 W frags =====
__global__ __launch_bounds__(256) void k_prep(const float* __restrict__ x,
                                              unsigned short* __restrict__ o,
                                              const int* __restrict__ dst,
                                              int* __restrict__ bhist,
                                              float* __restrict__ zbase,
                                              const float* __restrict__ Wl0,
                                              const float* __restrict__ Wr0,
                                              unsigned short* __restrict__ wfragA){
    __shared__ int lh[NB];
    int b = blockIdx.x, t = threadIdx.x;
    if (b < CVT_BLOCKS){
        int base = b*1024 + t;                 // float4 units
        #pragma unroll
        for (int k2 = 0; k2 < 4; ++k2){
            int i = base + k2*256;
            if (i < (N_NODES*FDIM)/4){
                float4 v = ((const float4*)x)[i];
                ushort4 r;
                r.x = f2bf(v.x); r.y = f2bf(v.y); r.z = f2bf(v.z); r.w = f2bf(v.w);
                ((ushort4*)o)[i] = r;
            }
        }
        // zero bnpartA (64KB) + bnpartB (64KB) + S (32KB)
        if (b < 160) zbase[(b << 8) + t] = 0.f;
    } else if (b < CVT_BLOCKS + PART_BLOCKS){
        for (int i = t; i < NB; i += 256) lh[i] = 0;
        __syncthreads();
        int base = (b - CVT_BLOCKS) * 4096;
        #pragma unroll
        for (int k = 0; k < 16; ++k){
            int e = base + k*256 + t;
            if (e < N_EDGES) atomicAdd(&lh[dst[e] >> 7], 1);
        }
        __syncthreads();
        for (int i = t; i < NB; i += 256) if (lh[i]) atomicAdd(&bhist[i], lh[i]);
    } else {
        build_wfrag(Wl0, Wr0, nullptr, t, wfragA);
    }
}

// ================= single-block exclusive scan of NB bucket sizes =================
__global__ __launch_bounds__(256) void k_bscan(const int* __restrict__ bhist,
                                               int* __restrict__ boff, int* __restrict__ cur){
    __shared__ int lds[256];
    int t = threadIdx.x;
    int base = t*4;
    int v0 = (base+0 < NB) ? bhist[base+0] : 0;
    int v1 = (base+1 < NB) ? bhist[base+1] : 0;
    int v2 = (base+2 < NB) ? bhist[base+2] : 0;
    int v3 = (base+3 < NB) ? bhist[base+3] : 0;
    lds[t] = v0+v1+v2+v3; __syncthreads();
    for (int off = 1; off < 256; off <<= 1){
        int add = (t >= off) ? lds[t-off] : 0; __syncthreads();
        lds[t] += add; __syncthreads();
    }
    int excl = (t > 0) ? lds[t-1] : 0;
    int p0 = excl, p1 = excl+v0, p2 = excl+v0+v1, p3 = excl+v0+v1+v2;
    if (base+0 < NB){ boff[base+0] = p0; cur[base+0] = p0; }
    if (base+1 < NB){ boff[base+1] = p1; cur[base+1] = p1; }
    if (base+2 < NB){ boff[base+2] = p2; cur[base+2] = p2; }
    if (base+3 < NB){ boff[base+3] = p3; cur[base+3] = p3; }
    if (t == 0) boff[NB] = N_EDGES;
}

// ================= partition edges into dst buckets, packed (src<<7)|dst_local =================
__global__ __launch_bounds__(256) void k_part(const int* __restrict__ src, const int* __restrict__ dst,
                                              int* __restrict__ cur, int* __restrict__ packed){
    __shared__ int lh[NB];
    __shared__ int lc[NB];
    int t = threadIdx.x;
    for (int i = t; i < NB; i += 256) lh[i] = 0;
    __syncthreads();
    int base = blockIdx.x * 4096;
    int d[16];
    #pragma unroll
    for (int k = 0; k < 16; ++k){
        int e = base + k*256 + t;
        d[k] = (e < N_EDGES) ? dst[e] : -1;
        if (d[k] >= 0) atomicAdd(&lh[d[k] >> 7], 1);
    }
    __syncthreads();
    for (int i = t; i < NB; i += 256) lc[i] = atomicAdd(&cur[i], lh[i]);
    __syncthreads();
    #pragma unroll
    for (int k = 0; k < 16; ++k){
        int e = base + k*256 + t;
        if (e < N_EDGES){
            int b = d[k] >> 7;
            int p = atomicAdd(&lc[b], 1);
            packed[p] = (src[e] << 7) | (d[k] & 127);
        }
    }
}

// ======== per-bucket counting sort: packed bucket -> CSR (rs + colb byte-offsets) ========
__global__ __launch_bounds__(256) void k_sort(const int* __restrict__ packed,
                                              const int* __restrict__ boff,
                                              int* __restrict__ rs, int* __restrict__ colb){
    __shared__ int hist[128];
    __shared__ int curs[128];
    int b = blockIdx.x, t = threadIdx.x;
    int e0 = boff[b], e1 = boff[b+1];
    if (t < 128) hist[t] = 0;
    __syncthreads();
    for (int e = e0 + t; e < e1; e += 256)
        atomicAdd(&hist[packed[e] & 127], 1);
    __syncthreads();
    int cnt = (t < 128) ? hist[t] : 0;
    __syncthreads();
    for (int off = 1; off < 128; off <<= 1){
        int add = (t < 128 && t >= off) ? hist[t-off] : 0;
        __syncthreads();
        if (t < 128) hist[t] += add;
        __syncthreads();
    }
    int nbase = b << 7;
    int nloc = min(128, N_NODES - nbase);
    if (t < nloc){
        int excl = hist[t] - cnt;
        rs[nbase + t] = e0 + excl;
        curs[t] = excl;
    }
    __syncthreads();
    for (int e = e0 + t; e < e1; e += 256){
        int v = packed[e];
        int p = atomicAdd(&curs[v & 127], 1);
        colb[e0 + p] = v & 0xFFFFFF80;        // src*128 = byte offset of bf16 row
    }
    if (b == 0 && t == 0) rs[N_NODES] = N_EDGES;
}

// ============ bf16 gather-mean: wave per node, 16 lanes x 8B, fp32 accum, bf16 out ============
__global__ __launch_bounds__(256) void k_agg(
    const unsigned short* __restrict__ xin, const int* __restrict__ rs,
    const int* __restrict__ colb, unsigned short* __restrict__ agg)
{
    int t = threadIdx.x;
    int lane = t & 63;
    int sub = lane >> 4;          // edge slot 0..3
    int q   = lane & 15;          // 8-byte chunk
    const char* xb = (const char*)xin + (q << 3);
    int wid = (blockIdx.x << 2) + (t >> 6);
    const int nw = gridDim.x << 2;
    for (int n = wid; n < N_NODES; n += nw){
        int e0 = __builtin_amdgcn_readfirstlane(rs[n]);
        int e1 = __builtin_amdgcn_readfirstlane(rs[n+1]);
        float ax=0.f, ay=0.f, az=0.f, aw=0.f;
        for (int e = e0; e < e1; e += 16){
            int i0 = e + sub, i1 = e + 4 + sub, i2 = e + 8 + sub, i3 = e + 12 + sub;
            if (i0 < e1){
                uint2 u = *(const uint2*)(xb + colb[i0]);
                ax += __uint_as_float(u.x << 16); ay += __uint_as_float(u.x & 0xffff0000u);
                az += __uint_as_float(u.y << 16); aw += __uint_as_float(u.y & 0xffff0000u);
            }
            if (i1 < e1){
                uint2 u = *(const uint2*)(xb + colb[i1]);
                ax += __uint_as_float(u.x << 16); ay += __uint_as_float(u.x & 0xffff0000u);
                az += __uint_as_float(u.y << 16); aw += __uint_as_float(u.y & 0xffff0000u);
            }
            if (i2 < e1){
                uint2 u = *(const uint2*)(xb + colb[i2]);
                ax += __uint_as_float(u.x << 16); ay += __uint_as_float(u.x & 0xffff0000u);
                az += __uint_as_float(u.y << 16); aw += __uint_as_float(u.y & 0xffff0000u);
            }
            if (i3 < e1){
                uint2 u = *(const uint2*)(xb + colb[i3]);
                ax += __uint_as_float(u.x << 16); ay += __uint_as_float(u.x & 0xffff0000u);
                az += __uint_as_float(u.y << 16); aw += __uint_as_float(u.y & 0xffff0000u);
            }
        }
        ax += __shfl_xor(ax, 16, 64); ay += __shfl_xor(ay, 16, 64);
        az += __shfl_xor(az, 16, 64); aw += __shfl_xor(aw, 16, 64);
        ax += __shfl_xor(ax, 32, 64); ay += __shfl_xor(ay, 32, 64);
        az += __shfl_xor(az, 32, 64); aw += __shfl_xor(aw, 32, 64);
        if (sub == 0){
            float rd = 1.f / fmaxf((float)(e1 - e0), 1.f);
            ushort4 o;
            o.x = f2bf(ax*rd); o.y = f2bf(ay*rd);
            o.z = f2bf(az*rd); o.w = f2bf(aw*rd);
            *(ushort4*)((char*)agg + (((size_t)n) << 7) + (q << 3)) = o;
        }
    }
}

// ============ MFMA dual-GEMM: precomputed W frags (8 x 16B coalesced loads) ============
template<bool AFF>
__global__ __launch_bounds__(256) void k_gemm(
    const unsigned short* __restrict__ agg,   // bf16 mean-agg rows
    const unsigned short* __restrict__ xin,   // bf16 root-branch rows
    unsigned short* __restrict__ hout,        // layer-1 h out (bf16); unused if AFF
    const int* __restrict__ rs, const int* __restrict__ batch,
    const unsigned short* __restrict__ wfrag, // precomputed per-lane W fragments
    const float* __restrict__ bbias, const float* __restrict__ bdelta,
    float* __restrict__ bnpart, float* __restrict__ S)
{
    __shared__ float sS[8*64];     // per-block graph-pool bins (AFF only)
    int t = threadIdx.x;
    int lane = t & 63;
    int jt = t >> 6;
    int g = lane >> 4, r = lane & 15;
    int j = (jt << 4) + r;

    const bf16x8* wf = (const bf16x8*)(wfrag + (size_t)t * 64);
    bf16x8 wlh[2] = {wf[0], wf[1]};
    bf16x8 wll[2] = {wf[2], wf[3]};
    bf16x8 wrh[2] = {wf[4], wf[5]};
    bf16x8 wrl[2] = {wf[6], wf[7]};

    float bb = bbias[j];
    float bd = AFF ? bdelta[j] : 0.f;

    int gbase = 0, span = 0;
    if (AFF){
        for (int i = t; i < 512; i += 256) sS[i] = 0.f;
        int nfirst = blockIdx.x * (TPB*16);
        int nlast  = min(nfirst + TPB*16 - 1, N_NODES - 1);
        gbase = batch[nfirst];
        span  = batch[nlast] - gbase + 1;
        __syncthreads();
    }

    float bs = 0.f, bq = 0.f;
    int c0 = blockIdx.x * TPB;    // 2 tiles, both valid (3125*2 == NTILES)

    auto LOADT = [&](int tile, bf16x8* A, bf16x8* X, int4& R, int& R5, int4& B){
        size_t rowoff = (((size_t)((tile << 4) + r)) << 6) + (g << 3);
        const bf16x8* pa = (const bf16x8*)(agg + rowoff);
        const bf16x8* px = (const bf16x8*)(xin + rowoff);
        A[0] = pa[0]; A[1] = pa[4];
        X[0] = px[0]; X[1] = px[4];
        if (AFF){
            int nb = (tile << 4) + (g << 2);
            R  = *(const int4*)(rs + nb);
            R5 = rs[nb + 4];
            B  = *(const int4*)(batch + nb);
        }
    };

    auto POOL = [&](int gr, float hv){
        int lg = gr - gbase;
        if (lg < 8) atomicAdd(&sS[(lg << 6) + j], hv);
        else        atomicAdd(&S[(gr << 6) + j], hv);
    };

    auto COMPUTE = [&](int tile, const bf16x8* A, const bf16x8* X,
                       const int4& R, int R5, const int4& B){
        f32x4 accA = {0.f, 0.f, 0.f, 0.f};
        f32x4 accX = {0.f, 0.f, 0.f, 0.f};
        accA = __builtin_amdgcn_mfma_f32_16x16x32_bf16(A[0], wlh[0], accA, 0, 0, 0);
        accA = __builtin_amdgcn_mfma_f32_16x16x32_bf16(A[0], wll[0], accA, 0, 0, 0);
        accA = __builtin_amdgcn_mfma_f32_16x16x32_bf16(A[1], wlh[1], accA, 0, 0, 0);
        accA = __builtin_amdgcn_mfma_f32_16x16x32_bf16(A[1], wll[1], accA, 0, 0, 0);
        accX = __builtin_amdgcn_mfma_f32_16x16x32_bf16(X[0], wrh[0], accX, 0, 0, 0);
        accX = __builtin_amdgcn_mfma_f32_16x16x32_bf16(X[0], wrl[0], accX, 0, 0, 0);
        accX = __builtin_amdgcn_mfma_f32_16x16x32_bf16(X[1], wrh[1], accX, 0, 0, 0);
        accX = __builtin_amdgcn_mfma_f32_16x16x32_bf16(X[1], wrl[1], accX, 0, 0, 0);

        int nb = (tile << 4) + (g << 2);
        if (AFF){
            float hv;
            hv = accA[0] + accX[0] + bb + ((R.y - R.x) > 0 ? bd : 0.f);
            hv = leaky(hv); bs += hv; bq += hv*hv; POOL(B.x, hv);
            hv = accA[1] + accX[1] + bb + ((R.z - R.y) > 0 ? bd : 0.f);
            hv = leaky(hv); bs += hv; bq += hv*hv; POOL(B.y, hv);
            hv = accA[2] + accX[2] + bb + ((R.w - R.z) > 0 ? bd : 0.f);
            hv = leaky(hv); bs += hv; bq += hv*hv; POOL(B.z, hv);
            hv = accA[3] + accX[3] + bb + ((R5 - R.w) > 0 ? bd : 0.f);
            hv = leaky(hv); bs += hv; bq += hv*hv; POOL(B.w, hv);
        } else {
            #pragma unroll
            for (int q2 = 0; q2 < 4; ++q2){
                float hv = leaky(accA[q2] + accX[q2] + bb);
                unsigned short h16 = f2bf(hv);
                float hr = bf2f(h16);
                hout[((size_t)(nb + q2) << 6) + j] = h16;
                bs += hr; bq += hr*hr;
            }
        }
    };

    bf16x8 Aa[2], Xa[2], Ab[2], Xb[2];
    int4 Ra = {0,0,0,0}, Rb = {0,0,0,0}, Ba = {0,0,0,0}, Bb = {0,0,0,0};
    int R5a = 0, R5b = 0;

    LOADT(c0 + 0, Aa, Xa, Ra, R5a, Ba);
    LOADT(c0 + 1, Ab, Xb, Rb, R5b, Bb);
    COMPUTE(c0 + 0, Aa, Xa, Ra, R5a, Ba);
    COMPUTE(c0 + 1, Ab, Xb, Rb, R5b, Bb);

    bs += __shfl_xor(bs, 16, 64); bs += __shfl_xor(bs, 32, 64);
    bq += __shfl_xor(bq, 16, 64); bq += __shfl_xor(bq, 32, 64);
    if (lane < 16){
        float* bp = bnpart + ((blockIdx.x & (BN_SLOTS-1)) * 128);
        atomicAdd(&bp[(jt << 4) + lane], bs);
        atomicAdd(&bp[64 + (jt << 4) + lane], bq);
    }

    if (AFF){
        __syncthreads();
        int sp = min(span, 8);
        for (int i = t; i < (sp << 6); i += 256){
            float v = sS[i];
            if (v != 0.f) atomicAdd(&S[((gbase + (i >> 6)) << 6) + (i & 63)], v);
        }
    }
}

// ==== BN finalize (256 thr): reduce slots; FOLD: fold next-layer biases + build W frags ====
template<bool FOLD>
__global__ __launch_bounds__(256) void k_bnfin(
    const float* __restrict__ bnpart,
    const float* __restrict__ gamma, const float* __restrict__ beta,
    const float* __restrict__ Wl_nx, const float* __restrict__ Wr_nx,
    const float* __restrict__ bl_nx,
    float* __restrict__ scale, float* __restrict__ shift,
    float* __restrict__ bbias, float* __restrict__ bdelta,
    unsigned short* __restrict__ wfragB)
{
    __shared__ float ssh[64];
    __shared__ float ssc[64];
    int t = threadIdx.x;
    if (t < 64){
        int j = t;
        float s = 0.f, q = 0.f;
        #pragma unroll 8
        for (int i = 0; i < BN_SLOTS; ++i){
            s += bnpart[i*128 + j];
            q += bnpart[i*128 + 64 + j];
        }
        float mu  = s * (1.0f/N_NODES);
        float var = q * (1.0f/N_NODES) - mu*mu;
        float sc  = gamma[j] * rsqrtf(var + EPSV);
        float sh  = beta[j] - mu*sc;
        scale[j] = sc; shift[j] = sh;
        ssh[j] = sh; ssc[j] = sc;
    }
    __syncthreads();
    if (FOLD){
        if (t < 64){
            int j = t;
            float bbv = bl_nx[j], bdv = 0.f;
            #pragma unroll 8
            for (int k = 0; k < 64; ++k){
                bbv += ssh[k] * Wr_nx[(k << 6) + j];
                bdv += ssh[k] * Wl_nx[(k << 6) + j];
            }
            bbias[j] = bbv; bdelta[j] = bdv;
        }
        build_wfrag(Wl_nx, Wr_nx, ssc, t, wfragB);
    }
}

// ============ final MLP (pool finalize fused): one block per graph ============
__global__ __launch_bounds__(256) void k_mlp(
    const float* __restrict__ S, const int* __restrict__ batch,
    const float* __restrict__ scale, const float* __restrict__ shift,
    const float* __restrict__ gf,
    const float* __restrict__ Wm0, const float* __restrict__ bm0,
    const float* __restrict__ Wm1, const float* __restrict__ bm1,
    const float* __restrict__ Wm2, const float* __restrict__ bm2,
    float* __restrict__ out)
{
    __shared__ int seg[2];
    __shared__ float z[128];
    __shared__ float h1[256];
    __shared__ float h2[128];
    int g = blockIdx.x, t = threadIdx.x;
    if (t < 2){
        int target = g + t;
        int lo = 0, hi = N_NODES;
        while (lo < hi){ int mid = (lo+hi)>>1; if (batch[mid] < target) lo = mid+1; else hi = mid; }
        seg[t] = lo;
    }
    __syncthreads();
    float cnt = (float)(seg[1] - seg[0]);
    if (t < 64)
        z[t] = (scale[t]*S[(g<<6)+t] + cnt*shift[t]) / fmaxf(cnt, 1.f);
    else if (t < 128)
        z[t] = gf[g*64 + (t-64)];
    __syncthreads();
    float acc = bm0[t];
    #pragma unroll 8
    for (int k = 0; k < 128; ++k) acc += z[k]*Wm0[k*256 + t];
    h1[t] = leaky(acc);
    __syncthreads();
    if (t < 128){
        float a = bm1[t];
        #pragma unroll 8
        for (int k = 0; k < 256; ++k) a += h1[k]*Wm1[k*128 + t];
        h2[t] = leaky(a);
    }
    __syncthreads();
    if (t < 2){
        float a = bm2[t];
        for (int k = 0; k < 128; ++k) a += h2[k]*Wm2[k*2 + t];
        out[g*2 + t] = a;
    }
}

extern "C" void kernel_launch(void* const* d_in, const int* in_sizes, int n_in,
                              void* d_out, int out_size, void* d_ws, size_t ws_size,
                              hipStream_t stream) {
    const float* x     = (const float*)d_in[0];
    const int*   ei    = (const int*)d_in[1];
    const float* gf    = (const float*)d_in[2];
    const int*   batch = (const int*)d_in[3];
    const float* Wl0 = (const float*)d_in[4];
    const float* bl0 = (const float*)d_in[5];
    const float* Wr0 = (const float*)d_in[6];
    const float* g0  = (const float*)d_in[7];
    const float* b0  = (const float*)d_in[8];
    const float* Wl1 = (const float*)d_in[9];
    const float* bl1 = (const float*)d_in[10];
    const float* Wr1 = (const float*)d_in[11];
    const float* g1  = (const float*)d_in[12];
    const float* b1  = (const float*)d_in[13];
    const float* Wm0 = (const float*)d_in[14];
    const float* bm0 = (const float*)d_in[15];
    const float* Wm1 = (const float*)d_in[16];
    const float* bm1 = (const float*)d_in[17];
    const float* Wm2 = (const float*)d_in[18];
    const float* bm2 = (const float*)d_in[19];

    // ---- workspace ----
    int*   bhist  = (int*)d_ws;                      // [NB]
    int*   boff   = bhist + NB;                      // [NB+1]
    int*   cur    = boff + NB + 1;                   // [NB]
    int*   packed = (int*)d_ws + 2348;               // [E]
    int*   rs     = packed + N_EDGES;                // [N+1] (pad 100004)
    int*   colb   = rs + 100004;                     // [E] byte offsets
    unsigned short* xbf   = (unsigned short*)(colb + N_EDGES);  // [N*64] bf16 x
    unsigned short* h1bf  = xbf + (size_t)N_NODES*FDIM;         // [N*64] bf16 h1
    unsigned short* aggbf = h1bf + (size_t)N_NODES*FDIM;        // [N*64] bf16 agg
    float* bnpartA = (float*)(aggbf + (size_t)N_NODES*FDIM);    // [BN_SLOTS*128]
    float* bnpartB = bnpartA + BN_SLOTS*128;         // [BN_SLOTS*128]
    float* S       = bnpartB + BN_SLOTS*128;         // [128*64]
    float* scale0  = S + N_GRAPHS*FDIM;
    float* shift0  = scale0 + 64;
    float* scale1  = scale0 + 128;
    float* shift1  = scale0 + 192;
    float* bbias   = scale0 + 256;
    float* bdelta  = scale0 + 320;
    unsigned short* wfragA = (unsigned short*)(scale0 + 384);   // [16384] bf16 (32 KB)
    unsigned short* wfragB = wfragA + 16384;                    // [16384] bf16 (32 KB)

    const int* srcp = ei;
    const int* dstp = ei + N_EDGES;

    // ---- bucketed CSR build + x conversion + scratch zero + layer-1 W frags (merged) ----
    hipMemsetAsync(bhist, 0, NB*sizeof(int), stream);
    k_prep<<<CVT_BLOCKS + PART_BLOCKS + 1, 256, 0, stream>>>(
        x, xbf, dstp, bhist, bnpartA, Wl0, Wr0, wfragA);
    k_bscan<<<1, 256, 0, stream>>>(bhist, boff, cur);
    k_part<<<PART_BLOCKS, 256, 0, stream>>>(srcp, dstp, cur, packed);
    k_sort<<<NB, 256, 0, stream>>>(packed, boff, rs, colb);

    // ---- layer 1 ----
    k_agg<<<2048, 256, 0, stream>>>(xbf, rs, colb, aggbf);
    k_gemm<false><<<GEMM_BLOCKS, 256, 0, stream>>>(
        aggbf, xbf, h1bf, rs, batch,
        wfragA, bl0, nullptr, bnpartA, nullptr);
    k_bnfin<true><<<1, 256, 0, stream>>>(bnpartA, g0, b0, Wl1, Wr1, bl1,
                                         scale0, shift0, bbias, bdelta, wfragB);

    // ---- layer 2 (h2 never materialized; pooling fused) ----
    k_agg<<<2048, 256, 0, stream>>>(h1bf, rs, colb, aggbf);
    k_gemm<true><<<GEMM_BLOCKS, 256, 0, stream>>>(
        aggbf, h1bf, nullptr, rs, batch,
        wfragB, bbias, bdelta, bnpartB, S);
    k_bnfin<false><<<1, 256, 0, stream>>>(bnpartB, g1, b1, nullptr, nullptr, nullptr,
                                          scale1, shift1, nullptr, nullptr, nullptr);

    // ---- pooling finalize + MLP ----
    k_mlp<<<N_GRAPHS, 256, 0, stream>>>(S, batch, scale1, shift1, gf,
                                        Wm0, bm0, Wm1, bm1, Wm2, bm2, (float*)d_out);
}

// Round 17
// 264.741 us; speedup vs baseline: 1.0987x; 1.0987x over previous
//
#include <hip/hip_runtime.h>

#define N_NODES 100000
#define N_EDGES 1600000
#define N_GRAPHS 128
#define FDIM 64
#define EPSV 1e-5f
#define NEG 0.01f

#define NB 782              // ceil(N_NODES/128) dst-range buckets
#define PART_BLOCKS 391     // ceil(N_EDGES/4096)
#define CVT_BLOCKS 1563     // ceil(1.6M float4 / 1024 per block)
#define NTILES 6250         // N_NODES/16 (exact)
#define TPB 2               // tiles per gemm block
#define GEMM_BLOCKS 3125    // NTILES/TPB (exact)
#define BN_SLOTS 128        // low-contention BN scratch slots

typedef short bf16x8 __attribute__((ext_vector_type(8)));
typedef float f32x4  __attribute__((ext_vector_type(4)));
typedef unsigned short ushort8 __attribute__((ext_vector_type(8)));

__device__ __forceinline__ float leaky(float x){ return x >= 0.f ? x : NEG*x; }

__device__ __forceinline__ unsigned short f2bf(float x){          // RN-even
    unsigned u = __float_as_uint(x);
    return (unsigned short)((u + 0x7fffu + ((u >> 16) & 1u)) >> 16);
}
__device__ __forceinline__ float bf2f(unsigned short b){
    return __uint_as_float(((unsigned)b) << 16);
}

// ===== merged: fp32->bf16 convert + bucket histogram (+ zero bnpartA/B and S) =====
__global__ __launch_bounds__(256) void k_prep(const float* __restrict__ x,
                                              unsigned short* __restrict__ o,
                                              const int* __restrict__ dst,
                                              int* __restrict__ bhist,
                                              float* __restrict__ zbase){
    __shared__ int lh[NB];
    int b = blockIdx.x, t = threadIdx.x;
    if (b < CVT_BLOCKS){
        int base = b*1024 + t;                 // float4 units
        #pragma unroll
        for (int k2 = 0; k2 < 4; ++k2){
            int i = base + k2*256;
            if (i < (N_NODES*FDIM)/4){
                float4 v = ((const float4*)x)[i];
                ushort4 r;
                r.x = f2bf(v.x); r.y = f2bf(v.y); r.z = f2bf(v.z); r.w = f2bf(v.w);
                ((ushort4*)o)[i] = r;
            }
        }
        // zero bnpartA (64KB) + bnpartB (64KB) + S (32KB) = 160 blocks x 1KB
        if (b < 160) zbase[(b << 8) + t] = 0.f;
    } else {
        for (int i = t; i < NB; i += 256) lh[i] = 0;
        __syncthreads();
        int base = (b - CVT_BLOCKS) * 4096;
        #pragma unroll
        for (int k = 0; k < 16; ++k){
            int e = base + k*256 + t;
            if (e < N_EDGES) atomicAdd(&lh[dst[e] >> 7], 1);
        }
        __syncthreads();
        for (int i = t; i < NB; i += 256) if (lh[i]) atomicAdd(&bhist[i], lh[i]);
    }
}

// ================= single-block exclusive scan of NB bucket sizes =================
__global__ __launch_bounds__(256) void k_bscan(const int* __restrict__ bhist,
                                               int* __restrict__ boff, int* __restrict__ cur){
    __shared__ int lds[256];
    int t = threadIdx.x;
    int base = t*4;
    int v0 = (base+0 < NB) ? bhist[base+0] : 0;
    int v1 = (base+1 < NB) ? bhist[base+1] : 0;
    int v2 = (base+2 < NB) ? bhist[base+2] : 0;
    int v3 = (base+3 < NB) ? bhist[base+3] : 0;
    lds[t] = v0+v1+v2+v3; __syncthreads();
    for (int off = 1; off < 256; off <<= 1){
        int add = (t >= off) ? lds[t-off] : 0; __syncthreads();
        lds[t] += add; __syncthreads();
    }
    int excl = (t > 0) ? lds[t-1] : 0;
    int p0 = excl, p1 = excl+v0, p2 = excl+v0+v1, p3 = excl+v0+v1+v2;
    if (base+0 < NB){ boff[base+0] = p0; cur[base+0] = p0; }
    if (base+1 < NB){ boff[base+1] = p1; cur[base+1] = p1; }
    if (base+2 < NB){ boff[base+2] = p2; cur[base+2] = p2; }
    if (base+3 < NB){ boff[base+3] = p3; cur[base+3] = p3; }
    if (t == 0) boff[NB] = N_EDGES;
}

// ================= partition edges into dst buckets, packed (src<<7)|dst_local =================
__global__ __launch_bounds__(256) void k_part(const int* __restrict__ src, const int* __restrict__ dst,
                                              int* __restrict__ cur, int* __restrict__ packed){
    __shared__ int lh[NB];
    __shared__ int lc[NB];
    int t = threadIdx.x;
    for (int i = t; i < NB; i += 256) lh[i] = 0;
    __syncthreads();
    int base = blockIdx.x * 4096;
    int d[16];
    #pragma unroll
    for (int k = 0; k < 16; ++k){
        int e = base + k*256 + t;
        d[k] = (e < N_EDGES) ? dst[e] : -1;
        if (d[k] >= 0) atomicAdd(&lh[d[k] >> 7], 1);
    }
    __syncthreads();
    for (int i = t; i < NB; i += 256) lc[i] = atomicAdd(&cur[i], lh[i]);
    __syncthreads();
    #pragma unroll
    for (int k = 0; k < 16; ++k){
        int e = base + k*256 + t;
        if (e < N_EDGES){
            int b = d[k] >> 7;
            int p = atomicAdd(&lc[b], 1);
            packed[p] = (src[e] << 7) | (d[k] & 127);
        }
    }
}

// ======== per-bucket counting sort: packed bucket -> CSR (rs + colb byte-offsets) ========
__global__ __launch_bounds__(256) void k_sort(const int* __restrict__ packed,
                                              const int* __restrict__ boff,
                                              int* __restrict__ rs, int* __restrict__ colb){
    __shared__ int hist[128];
    __shared__ int curs[128];
    int b = blockIdx.x, t = threadIdx.x;
    int e0 = boff[b], e1 = boff[b+1];
    if (t < 128) hist[t] = 0;
    __syncthreads();
    for (int e = e0 + t; e < e1; e += 256)
        atomicAdd(&hist[packed[e] & 127], 1);
    __syncthreads();
    int cnt = (t < 128) ? hist[t] : 0;
    __syncthreads();
    for (int off = 1; off < 128; off <<= 1){
        int add = (t < 128 && t >= off) ? hist[t-off] : 0;
        __syncthreads();
        if (t < 128) hist[t] += add;
        __syncthreads();
    }
    int nbase = b << 7;
    int nloc = min(128, N_NODES - nbase);
    if (t < nloc){
        int excl = hist[t] - cnt;
        rs[nbase + t] = e0 + excl;
        curs[t] = excl;
    }
    __syncthreads();
    for (int e = e0 + t; e < e1; e += 256){
        int v = packed[e];
        int p = atomicAdd(&curs[v & 127], 1);
        colb[e0 + p] = v & 0xFFFFFF80;        // src*128 = byte offset of bf16 row
    }
    if (b == 0 && t == 0) rs[N_NODES] = N_EDGES;
}

// ==== bf16 gather-mean, HIGH-MLP: 8 edge slots x 8 lanes x 16B, 32 edges in flight ====
__global__ __launch_bounds__(256) void k_agg(
    const unsigned short* __restrict__ xin, const int* __restrict__ rs,
    const int* __restrict__ colb, unsigned short* __restrict__ agg)
{
    int t = threadIdx.x;
    int lane = t & 63;
    int sub = lane >> 3;          // edge slot 0..7
    int q   = lane & 7;           // 16-byte chunk within 128-B row
    const char* xb = (const char*)xin + (q << 4);
    int wid = (blockIdx.x << 2) + (t >> 6);
    const int nw = gridDim.x << 2;
    for (int n = wid; n < N_NODES; n += nw){
        int e0 = __builtin_amdgcn_readfirstlane(rs[n]);
        int e1 = __builtin_amdgcn_readfirstlane(rs[n+1]);
        float a0=0.f,a1=0.f,a2=0.f,a3=0.f,a4=0.f,a5=0.f,a6=0.f,a7=0.f;
        for (int e = e0; e < e1; e += 32){
            int i0 = e + sub, i1 = e + 8 + sub, i2 = e + 16 + sub, i3 = e + 24 + sub;
            bool v0 = i0 < e1, v1 = i1 < e1, v2 = i2 < e1, v3 = i3 < e1;
            int c0, c1, c2, c3;
            if (v0) c0 = colb[i0];
            if (v1) c1 = colb[i1];
            if (v2) c2 = colb[i2];
            if (v3) c3 = colb[i3];
            if (v0){
                uint4 u = *(const uint4*)(xb + c0);
                a0 += __uint_as_float(u.x << 16); a1 += __uint_as_float(u.x & 0xffff0000u);
                a2 += __uint_as_float(u.y << 16); a3 += __uint_as_float(u.y & 0xffff0000u);
                a4 += __uint_as_float(u.z << 16); a5 += __uint_as_float(u.z & 0xffff0000u);
                a6 += __uint_as_float(u.w << 16); a7 += __uint_as_float(u.w & 0xffff0000u);
            }
            if (v1){
                uint4 u = *(const uint4*)(xb + c1);
                a0 += __uint_as_float(u.x << 16); a1 += __uint_as_float(u.x & 0xffff0000u);
                a2 += __uint_as_float(u.y << 16); a3 += __uint_as_float(u.y & 0xffff0000u);
                a4 += __uint_as_float(u.z << 16); a5 += __uint_as_float(u.z & 0xffff0000u);
                a6 += __uint_as_float(u.w << 16); a7 += __uint_as_float(u.w & 0xffff0000u);
            }
            if (v2){
                uint4 u = *(const uint4*)(xb + c2);
                a0 += __uint_as_float(u.x << 16); a1 += __uint_as_float(u.x & 0xffff0000u);
                a2 += __uint_as_float(u.y << 16); a3 += __uint_as_float(u.y & 0xffff0000u);
                a4 += __uint_as_float(u.z << 16); a5 += __uint_as_float(u.z & 0xffff0000u);
                a6 += __uint_as_float(u.w << 16); a7 += __uint_as_float(u.w & 0xffff0000u);
            }
            if (v3){
                uint4 u = *(const uint4*)(xb + c3);
                a0 += __uint_as_float(u.x << 16); a1 += __uint_as_float(u.x & 0xffff0000u);
                a2 += __uint_as_float(u.y << 16); a3 += __uint_as_float(u.y & 0xffff0000u);
                a4 += __uint_as_float(u.z << 16); a5 += __uint_as_float(u.z & 0xffff0000u);
                a6 += __uint_as_float(u.w << 16); a7 += __uint_as_float(u.w & 0xffff0000u);
            }
        }
        // reduce over 8 slots (lane bits 3..5)
        a0 += __shfl_xor(a0, 8, 64);  a1 += __shfl_xor(a1, 8, 64);
        a2 += __shfl_xor(a2, 8, 64);  a3 += __shfl_xor(a3, 8, 64);
        a4 += __shfl_xor(a4, 8, 64);  a5 += __shfl_xor(a5, 8, 64);
        a6 += __shfl_xor(a6, 8, 64);  a7 += __shfl_xor(a7, 8, 64);
        a0 += __shfl_xor(a0, 16, 64); a1 += __shfl_xor(a1, 16, 64);
        a2 += __shfl_xor(a2, 16, 64); a3 += __shfl_xor(a3, 16, 64);
        a4 += __shfl_xor(a4, 16, 64); a5 += __shfl_xor(a5, 16, 64);
        a6 += __shfl_xor(a6, 16, 64); a7 += __shfl_xor(a7, 16, 64);
        a0 += __shfl_xor(a0, 32, 64); a1 += __shfl_xor(a1, 32, 64);
        a2 += __shfl_xor(a2, 32, 64); a3 += __shfl_xor(a3, 32, 64);
        a4 += __shfl_xor(a4, 32, 64); a5 += __shfl_xor(a5, 32, 64);
        a6 += __shfl_xor(a6, 32, 64); a7 += __shfl_xor(a7, 32, 64);
        if (sub == 0){
            float rd = 1.f / fmaxf((float)(e1 - e0), 1.f);
            ushort8 o;
            o[0] = f2bf(a0*rd); o[1] = f2bf(a1*rd);
            o[2] = f2bf(a2*rd); o[3] = f2bf(a3*rd);
            o[4] = f2bf(a4*rd); o[5] = f2bf(a5*rd);
            o[6] = f2bf(a6*rd); o[7] = f2bf(a7*rd);
            *(ushort8*)((char*)agg + (((size_t)n) << 7) + (q << 4)) = o;
        }
    }
}

// ============ MFMA dual-GEMM (all-bf16), TPB=2, wide grid, low-contention BN ============
template<bool AFF>
__global__ __launch_bounds__(256) void k_gemm(
    const unsigned short* __restrict__ agg,   // bf16 mean-agg rows
    const unsigned short* __restrict__ xin,   // bf16 root-branch rows
    unsigned short* __restrict__ hout,        // layer-1 h out (bf16); unused if AFF
    const int* __restrict__ rs, const int* __restrict__ batch,
    const float* __restrict__ Wl, const float* __restrict__ Wr,
    const float* __restrict__ scale,
    const float* __restrict__ bbias, const float* __restrict__ bdelta,
    float* __restrict__ bnpart, float* __restrict__ S)
{
    __shared__ float sS[8*64];     // per-block graph-pool bins (AFF only)
    int t = threadIdx.x;
    int lane = t & 63;
    int jt = t >> 6;
    int g = lane >> 4, r = lane & 15;
    int j = (jt << 4) + r;

    // W fragments: B[k][j], k = ks*32 + 8g + i, scale-folded, trunc hi/lo split
    bf16x8 wlh[2], wll[2], wrh[2], wrl[2];
    #pragma unroll
    for (int ks = 0; ks < 2; ++ks){
        #pragma unroll
        for (int i = 0; i < 8; ++i){
            int k = (ks << 5) + (g << 3) + i;
            float s = AFF ? scale[k] : 1.f;
            float wv = Wl[(k << 6) + j] * s;
            unsigned u = __float_as_uint(wv);
            wlh[ks][i] = (short)(u >> 16);
            float lf = wv - __uint_as_float(u & 0xffff0000u);
            wll[ks][i] = (short)(__float_as_uint(lf) >> 16);
            wv = Wr[(k << 6) + j] * s;
            u = __float_as_uint(wv);
            wrh[ks][i] = (short)(u >> 16);
            lf = wv - __uint_as_float(u & 0xffff0000u);
            wrl[ks][i] = (short)(__float_as_uint(lf) >> 16);
        }
    }

    float bb = bbias[j];
    float bd = AFF ? bdelta[j] : 0.f;

    int gbase = 0, span = 0;
    if (AFF){
        for (int i = t; i < 512; i += 256) sS[i] = 0.f;
        int nfirst = blockIdx.x * (TPB*16);
        int nlast  = min(nfirst + TPB*16 - 1, N_NODES - 1);
        gbase = batch[nfirst];
        span  = batch[nlast] - gbase + 1;
        __syncthreads();
    }

    float bs = 0.f, bq = 0.f;
    int c0 = blockIdx.x * TPB;    // 2 tiles, both valid (3125*2 == NTILES)

    auto LOADT = [&](int tile, bf16x8* A, bf16x8* X, int4& R, int& R5, int4& B){
        size_t rowoff = (((size_t)((tile << 4) + r)) << 6) + (g << 3);
        const bf16x8* pa = (const bf16x8*)(agg + rowoff);
        const bf16x8* px = (const bf16x8*)(xin + rowoff);
        A[0] = pa[0]; A[1] = pa[4];
        X[0] = px[0]; X[1] = px[4];
        if (AFF){
            int nb = (tile << 4) + (g << 2);
            R  = *(const int4*)(rs + nb);
            R5 = rs[nb + 4];
            B  = *(const int4*)(batch + nb);
        }
    };

    auto POOL = [&](int gr, float hv){
        int lg = gr - gbase;
        if (lg < 8) atomicAdd(&sS[(lg << 6) + j], hv);
        else        atomicAdd(&S[(gr << 6) + j], hv);
    };

    auto COMPUTE = [&](int tile, const bf16x8* A, const bf16x8* X,
                       const int4& R, int R5, const int4& B){
        f32x4 accA = {0.f, 0.f, 0.f, 0.f};
        f32x4 accX = {0.f, 0.f, 0.f, 0.f};
        accA = __builtin_amdgcn_mfma_f32_16x16x32_bf16(A[0], wlh[0], accA, 0, 0, 0);
        accA = __builtin_amdgcn_mfma_f32_16x16x32_bf16(A[0], wll[0], accA, 0, 0, 0);
        accA = __builtin_amdgcn_mfma_f32_16x16x32_bf16(A[1], wlh[1], accA, 0, 0, 0);
        accA = __builtin_amdgcn_mfma_f32_16x16x32_bf16(A[1], wll[1], accA, 0, 0, 0);
        accX = __builtin_amdgcn_mfma_f32_16x16x32_bf16(X[0], wrh[0], accX, 0, 0, 0);
        accX = __builtin_amdgcn_mfma_f32_16x16x32_bf16(X[0], wrl[0], accX, 0, 0, 0);
        accX = __builtin_amdgcn_mfma_f32_16x16x32_bf16(X[1], wrh[1], accX, 0, 0, 0);
        accX = __builtin_amdgcn_mfma_f32_16x16x32_bf16(X[1], wrl[1], accX, 0, 0, 0);

        int nb = (tile << 4) + (g << 2);
        if (AFF){
            float hv;
            hv = accA[0] + accX[0] + bb + ((R.y - R.x) > 0 ? bd : 0.f);
            hv = leaky(hv); bs += hv; bq += hv*hv; POOL(B.x, hv);
            hv = accA[1] + accX[1] + bb + ((R.z - R.y) > 0 ? bd : 0.f);
            hv = leaky(hv); bs += hv; bq += hv*hv; POOL(B.y, hv);
            hv = accA[2] + accX[2] + bb + ((R.w - R.z) > 0 ? bd : 0.f);
            hv = leaky(hv); bs += hv; bq += hv*hv; POOL(B.z, hv);
            hv = accA[3] + accX[3] + bb + ((R5 - R.w) > 0 ? bd : 0.f);
            hv = leaky(hv); bs += hv; bq += hv*hv; POOL(B.w, hv);
        } else {
            #pragma unroll
            for (int q2 = 0; q2 < 4; ++q2){
                float hv = leaky(accA[q2] + accX[q2] + bb);
                unsigned short h16 = f2bf(hv);
                float hr = bf2f(h16);
                hout[((size_t)(nb + q2) << 6) + j] = h16;
                bs += hr; bq += hr*hr;
            }
        }
    };

    bf16x8 Aa[2], Xa[2], Ab[2], Xb[2];
    int4 Ra = {0,0,0,0}, Rb = {0,0,0,0}, Ba = {0,0,0,0}, Bb = {0,0,0,0};
    int R5a = 0, R5b = 0;

    LOADT(c0 + 0, Aa, Xa, Ra, R5a, Ba);
    LOADT(c0 + 1, Ab, Xb, Rb, R5b, Bb);
    COMPUTE(c0 + 0, Aa, Xa, Ra, R5a, Ba);
    COMPUTE(c0 + 1, Ab, Xb, Rb, R5b, Bb);

    bs += __shfl_xor(bs, 16, 64); bs += __shfl_xor(bs, 32, 64);
    bq += __shfl_xor(bq, 16, 64); bq += __shfl_xor(bq, 32, 64);
    if (lane < 16){
        float* bp = bnpart + ((blockIdx.x & (BN_SLOTS-1)) * 128);
        atomicAdd(&bp[(jt << 4) + lane], bs);
        atomicAdd(&bp[64 + (jt << 4) + lane], bq);
    }

    if (AFF){
        __syncthreads();
        int sp = min(span, 8);
        for (int i = t; i < (sp << 6); i += 256){
            float v = sS[i];
            if (v != 0.f) atomicAdd(&S[((gbase + (i >> 6)) << 6) + (i & 63)], v);
        }
    }
}

// ============ BN finalize (256 thr): reduce slots; FOLD: fold next-layer biases ============
template<bool FOLD>
__global__ __launch_bounds__(256) void k_bnfin(
    const float* __restrict__ bnpart,
    const float* __restrict__ gamma, const float* __restrict__ beta,
    const float* __restrict__ Wl_nx, const float* __restrict__ Wr_nx,
    const float* __restrict__ bl_nx,
    float* __restrict__ scale, float* __restrict__ shift,
    float* __restrict__ bbias, float* __restrict__ bdelta)
{
    __shared__ float ssh[64];
    int t = threadIdx.x;
    if (t < 64){
        int j = t;
        float s = 0.f, q = 0.f;
        #pragma unroll 8
        for (int i = 0; i < BN_SLOTS; ++i){
            s += bnpart[i*128 + j];
            q += bnpart[i*128 + 64 + j];
        }
        float mu  = s * (1.0f/N_NODES);
        float var = q * (1.0f/N_NODES) - mu*mu;
        float sc  = gamma[j] * rsqrtf(var + EPSV);
        float sh  = beta[j] - mu*sc;
        scale[j] = sc; shift[j] = sh;
        ssh[j] = sh;
    }
    __syncthreads();
    if (FOLD && t < 64){
        int j = t;
        float bbv = bl_nx[j], bdv = 0.f;
        #pragma unroll 8
        for (int k = 0; k < 64; ++k){
            bbv += ssh[k] * Wr_nx[(k << 6) + j];
            bdv += ssh[k] * Wl_nx[(k << 6) + j];
        }
        bbias[j] = bbv; bdelta[j] = bdv;
    }
}

// ============ final MLP (pool finalize fused): one block per graph ============
__global__ __launch_bounds__(256) void k_mlp(
    const float* __restrict__ S, const int* __restrict__ batch,
    const float* __restrict__ scale, const float* __restrict__ shift,
    const float* __restrict__ gf,
    const float* __restrict__ Wm0, const float* __restrict__ bm0,
    const float* __restrict__ Wm1, const float* __restrict__ bm1,
    const float* __restrict__ Wm2, const float* __restrict__ bm2,
    float* __restrict__ out)
{
    __shared__ int seg[2];
    __shared__ float z[128];
    __shared__ float h1[256];
    __shared__ float h2[128];
    int g = blockIdx.x, t = threadIdx.x;
    if (t < 2){
        int target = g + t;
        int lo = 0, hi = N_NODES;
        while (lo < hi){ int mid = (lo+hi)>>1; if (batch[mid] < target) lo = mid+1; else hi = mid; }
        seg[t] = lo;
    }
    __syncthreads();
    float cnt = (float)(seg[1] - seg[0]);
    if (t < 64)
        z[t] = (scale[t]*S[(g<<6)+t] + cnt*shift[t]) / fmaxf(cnt, 1.f);
    else if (t < 128)
        z[t] = gf[g*64 + (t-64)];
    __syncthreads();
    float acc = bm0[t];
    #pragma unroll 8
    for (int k = 0; k < 128; ++k) acc += z[k]*Wm0[k*256 + t];
    h1[t] = leaky(acc);
    __syncthreads();
    if (t < 128){
        float a = bm1[t];
        #pragma unroll 8
        for (int k = 0; k < 256; ++k) a += h1[k]*Wm1[k*128 + t];
        h2[t] = leaky(a);
    }
    __syncthreads();
    if (t < 2){
        float a = bm2[t];
        for (int k = 0; k < 128; ++k) a += h2[k]*Wm2[k*2 + t];
        out[g*2 + t] = a;
    }
}

extern "C" void kernel_launch(void* const* d_in, const int* in_sizes, int n_in,
                              void* d_out, int out_size, void* d_ws, size_t ws_size,
                              hipStream_t stream) {
    const float* x     = (const float*)d_in[0];
    const int*   ei    = (const int*)d_in[1];
    const float* gf    = (const float*)d_in[2];
    const int*   batch = (const int*)d_in[3];
    const float* Wl0 = (const float*)d_in[4];
    const float* bl0 = (const float*)d_in[5];
    const float* Wr0 = (const float*)d_in[6];
    const float* g0  = (const float*)d_in[7];
    const float* b0  = (const float*)d_in[8];
    const float* Wl1 = (const float*)d_in[9];
    const float* bl1 = (const float*)d_in[10];
    const float* Wr1 = (const float*)d_in[11];
    const float* g1  = (const float*)d_in[12];
    const float* b1  = (const float*)d_in[13];
    const float* Wm0 = (const float*)d_in[14];
    const float* bm0 = (const float*)d_in[15];
    const float* Wm1 = (const float*)d_in[16];
    const float* bm1 = (const float*)d_in[17];
    const float* Wm2 = (const float*)d_in[18];
    const float* bm2 = (const float*)d_in[19];

    // ---- workspace ----
    int*   bhist  = (int*)d_ws;                      // [NB]
    int*   boff   = bhist + NB;                      // [NB+1]
    int*   cur    = boff + NB + 1;                   // [NB]
    int*   packed = (int*)d_ws + 2348;               // [E]
    int*   rs     = packed + N_EDGES;                // [N+1] (pad 100004)
    int*   colb   = rs + 100004;                     // [E] byte offsets
    unsigned short* xbf   = (unsigned short*)(colb + N_EDGES);  // [N*64] bf16 x
    unsigned short* h1bf  = xbf + (size_t)N_NODES*FDIM;         // [N*64] bf16 h1
    unsigned short* aggbf = h1bf + (size_t)N_NODES*FDIM;        // [N*64] bf16 agg
    float* bnpartA = (float*)(aggbf + (size_t)N_NODES*FDIM);    // [BN_SLOTS*128]
    float* bnpartB = bnpartA + BN_SLOTS*128;         // [BN_SLOTS*128]
    float* S       = bnpartB + BN_SLOTS*128;         // [128*64]
    float* scale0  = S + N_GRAPHS*FDIM;
    float* shift0  = scale0 + 64;
    float* scale1  = scale0 + 128;
    float* shift1  = scale0 + 192;
    float* bbias   = scale0 + 256;
    float* bdelta  = scale0 + 320;

    const int* srcp = ei;
    const int* dstp = ei + N_EDGES;

    // ---- bucketed CSR build + x conversion (merged; also zeroes bnpartA/B + S) ----
    hipMemsetAsync(bhist, 0, NB*sizeof(int), stream);
    k_prep<<<CVT_BLOCKS + PART_BLOCKS, 256, 0, stream>>>(x, xbf, dstp, bhist, bnpartA);
    k_bscan<<<1, 256, 0, stream>>>(bhist, boff, cur);
    k_part<<<PART_BLOCKS, 256, 0, stream>>>(srcp, dstp, cur, packed);
    k_sort<<<NB, 256, 0, stream>>>(packed, boff, rs, colb);

    // ---- layer 1 ----
    k_agg<<<2048, 256, 0, stream>>>(xbf, rs, colb, aggbf);
    k_gemm<false><<<GEMM_BLOCKS, 256, 0, stream>>>(
        aggbf, xbf, h1bf, rs, batch,
        Wl0, Wr0, nullptr, bl0, nullptr, bnpartA, nullptr);
    k_bnfin<true><<<1, 256, 0, stream>>>(bnpartA, g0, b0, Wl1, Wr1, bl1,
                                         scale0, shift0, bbias, bdelta);

    // ---- layer 2 (h2 never materialized; pooling fused) ----
    k_agg<<<2048, 256, 0, stream>>>(h1bf, rs, colb, aggbf);
    k_gemm<true><<<GEMM_BLOCKS, 256, 0, stream>>>(
        aggbf, h1bf, nullptr, rs, batch,
        Wl1, Wr1, scale0, bbias, bdelta, bnpartB, S);
    k_bnfin<false><<<1, 256, 0, stream>>>(bnpartB, g1, b1, nullptr, nullptr, nullptr,
                                          scale1, shift1, nullptr, nullptr);

    // ---- pooling finalize + MLP ----
    k_mlp<<<N_GRAPHS, 256, 0, stream>>>(S, batch, scale1, shift1, gf,
                                        Wm0, bm0, Wm1, bm1, Wm2, bm2, (float*)d_out);
}

// Round 18
// 264.348 us; speedup vs baseline: 1.1003x; 1.0015x over previous
//
#include <hip/hip_runtime.h>

#define N_NODES 100000
#define N_EDGES 1600000
#define N_GRAPHS 128
#define FDIM 64
#define EPSV 1e-5f
#define NEG 0.01f

#define NB 782              // ceil(N_NODES/128) dst-range buckets
#define PART_BLOCKS 391     // ceil(N_EDGES/4096)
#define CVT_BLOCKS 1563     // ceil(1.6M float4 / 1024 per block)
#define NTILES 6250         // N_NODES/16 (exact)
#define TPB 2               // tiles per gemm block
#define GEMM_BLOCKS 3125    // NTILES/TPB (exact)
#define BN_SLOTS 128        // low-contention BN scratch slots

typedef short bf16x8 __attribute__((ext_vector_type(8)));
typedef float f32x4  __attribute__((ext_vector_type(4)));
typedef unsigned short ushort8 __attribute__((ext_vector_type(8)));

__device__ __forceinline__ float leaky(float x){ return x >= 0.f ? x : NEG*x; }

__device__ __forceinline__ unsigned short f2bf(float x){          // RN-even
    unsigned u = __float_as_uint(x);
    return (unsigned short)((u + 0x7fffu + ((u >> 16) & 1u)) >> 16);
}
__device__ __forceinline__ float bf2f(unsigned short b){
    return __uint_as_float(((unsigned)b) << 16);
}

// ===== merged: fp32->bf16 convert + bucket histogram (+ zero bnpartA/B and S) =====
__global__ __launch_bounds__(256) void k_prep(const float* __restrict__ x,
                                              unsigned short* __restrict__ o,
                                              const int* __restrict__ dst,
                                              int* __restrict__ bhist,
                                              float* __restrict__ zbase){
    __shared__ int lh[NB];
    int b = blockIdx.x, t = threadIdx.x;
    if (b < CVT_BLOCKS){
        int base = b*1024 + t;                 // float4 units
        #pragma unroll
        for (int k2 = 0; k2 < 4; ++k2){
            int i = base + k2*256;
            if (i < (N_NODES*FDIM)/4){
                float4 v = ((const float4*)x)[i];
                ushort4 r;
                r.x = f2bf(v.x); r.y = f2bf(v.y); r.z = f2bf(v.z); r.w = f2bf(v.w);
                ((ushort4*)o)[i] = r;
            }
        }
        // zero bnpartA (64KB) + bnpartB (64KB) + S (32KB) = 160 blocks x 1KB
        if (b < 160) zbase[(b << 8) + t] = 0.f;
    } else {
        for (int i = t; i < NB; i += 256) lh[i] = 0;
        __syncthreads();
        int base = (b - CVT_BLOCKS) * 4096;
        #pragma unroll
        for (int k = 0; k < 16; ++k){
            int e = base + k*256 + t;
            if (e < N_EDGES) atomicAdd(&lh[dst[e] >> 7], 1);
        }
        __syncthreads();
        for (int i = t; i < NB; i += 256) if (lh[i]) atomicAdd(&bhist[i], lh[i]);
    }
}

// ================= single-block exclusive scan of NB bucket sizes =================
__global__ __launch_bounds__(256) void k_bscan(const int* __restrict__ bhist,
                                               int* __restrict__ boff, int* __restrict__ cur){
    __shared__ int lds[256];
    int t = threadIdx.x;
    int base = t*4;
    int v0 = (base+0 < NB) ? bhist[base+0] : 0;
    int v1 = (base+1 < NB) ? bhist[base+1] : 0;
    int v2 = (base+2 < NB) ? bhist[base+2] : 0;
    int v3 = (base+3 < NB) ? bhist[base+3] : 0;
    lds[t] = v0+v1+v2+v3; __syncthreads();
    for (int off = 1; off < 256; off <<= 1){
        int add = (t >= off) ? lds[t-off] : 0; __syncthreads();
        lds[t] += add; __syncthreads();
    }
    int excl = (t > 0) ? lds[t-1] : 0;
    int p0 = excl, p1 = excl+v0, p2 = excl+v0+v1, p3 = excl+v0+v1+v2;
    if (base+0 < NB){ boff[base+0] = p0; cur[base+0] = p0; }
    if (base+1 < NB){ boff[base+1] = p1; cur[base+1] = p1; }
    if (base+2 < NB){ boff[base+2] = p2; cur[base+2] = p2; }
    if (base+3 < NB){ boff[base+3] = p3; cur[base+3] = p3; }
    if (t == 0) boff[NB] = N_EDGES;
}

// ================= partition edges into dst buckets, packed (src<<7)|dst_local =================
__global__ __launch_bounds__(256) void k_part(const int* __restrict__ src, const int* __restrict__ dst,
                                              int* __restrict__ cur, int* __restrict__ packed){
    __shared__ int lh[NB];
    __shared__ int lc[NB];
    int t = threadIdx.x;
    for (int i = t; i < NB; i += 256) lh[i] = 0;
    __syncthreads();
    int base = blockIdx.x * 4096;
    int d[16];
    #pragma unroll
    for (int k = 0; k < 16; ++k){
        int e = base + k*256 + t;
        d[k] = (e < N_EDGES) ? dst[e] : -1;
        if (d[k] >= 0) atomicAdd(&lh[d[k] >> 7], 1);
    }
    __syncthreads();
    for (int i = t; i < NB; i += 256) lc[i] = atomicAdd(&cur[i], lh[i]);
    __syncthreads();
    #pragma unroll
    for (int k = 0; k < 16; ++k){
        int e = base + k*256 + t;
        if (e < N_EDGES){
            int b = d[k] >> 7;
            int p = atomicAdd(&lc[b], 1);
            packed[p] = (src[e] << 7) | (d[k] & 127);
        }
    }
}

// ======== per-bucket counting sort: packed bucket -> CSR (rs + colb byte-offsets) ========
__global__ __launch_bounds__(256) void k_sort(const int* __restrict__ packed,
                                              const int* __restrict__ boff,
                                              int* __restrict__ rs, int* __restrict__ colb){
    __shared__ int hist[128];
    __shared__ int curs[128];
    int b = blockIdx.x, t = threadIdx.x;
    int e0 = boff[b], e1 = boff[b+1];
    if (t < 128) hist[t] = 0;
    __syncthreads();
    for (int e = e0 + t; e < e1; e += 256)
        atomicAdd(&hist[packed[e] & 127], 1);
    __syncthreads();
    int cnt = (t < 128) ? hist[t] : 0;
    __syncthreads();
    for (int off = 1; off < 128; off <<= 1){
        int add = (t < 128 && t >= off) ? hist[t-off] : 0;
        __syncthreads();
        if (t < 128) hist[t] += add;
        __syncthreads();
    }
    int nbase = b << 7;
    int nloc = min(128, N_NODES - nbase);
    if (t < nloc){
        int excl = hist[t] - cnt;
        rs[nbase + t] = e0 + excl;
        curs[t] = excl;
    }
    __syncthreads();
    for (int e = e0 + t; e < e1; e += 256){
        int v = packed[e];
        int p = atomicAdd(&curs[v & 127], 1);
        colb[e0 + p] = v & 0xFFFFFF80;        // src*128 = byte offset of bf16 row
    }
    if (b == 0 && t == 0) rs[N_NODES] = N_EDGES;
}

// ==== bf16 gather-mean, PAIR + HIGH-MLP: 8 slots x 8 lanes x 16B, nodes (n,n+1) ====
__global__ __launch_bounds__(256) void k_agg(
    const unsigned short* __restrict__ xin, const int* __restrict__ rs,
    const int* __restrict__ colb, unsigned short* __restrict__ agg)
{
    int t = threadIdx.x;
    int lane = t & 63;
    int sub = lane >> 3;          // edge slot 0..7
    int q   = lane & 7;           // 16-byte chunk within 128-B row
    const char* xb = (const char*)xin + (q << 4);
    int wid = (blockIdx.x << 2) + (t >> 6);
    const int nw = gridDim.x << 2;
    for (int n0 = wid << 1; n0 < N_NODES; n0 += (nw << 1)){
        int e0a = __builtin_amdgcn_readfirstlane(rs[n0]);
        int e1a = __builtin_amdgcn_readfirstlane(rs[n0+1]);
        int e1b = __builtin_amdgcn_readfirstlane(rs[n0+2]);
        float a0=0.f,a1=0.f,a2=0.f,a3=0.f,a4=0.f,a5=0.f,a6=0.f,a7=0.f;
        float b0=0.f,b1=0.f,b2=0.f,b3=0.f,b4=0.f,b5=0.f,b6=0.f,b7=0.f;
        int ea = e0a + sub, eb = e1a + sub;
        while (ea < e1a || eb < e1b){
            int ia1 = ea + 8, ib1 = eb + 8;
            bool va0 = ea  < e1a, va1 = ia1 < e1a;
            bool vb0 = eb  < e1b, vb1 = ib1 < e1b;
            int ca0, ca1, cb0, cb1;
            if (va0) ca0 = colb[ea];
            if (va1) ca1 = colb[ia1];
            if (vb0) cb0 = colb[eb];
            if (vb1) cb1 = colb[ib1];
            if (va0){
                uint4 u = *(const uint4*)(xb + ca0);
                a0 += __uint_as_float(u.x << 16); a1 += __uint_as_float(u.x & 0xffff0000u);
                a2 += __uint_as_float(u.y << 16); a3 += __uint_as_float(u.y & 0xffff0000u);
                a4 += __uint_as_float(u.z << 16); a5 += __uint_as_float(u.z & 0xffff0000u);
                a6 += __uint_as_float(u.w << 16); a7 += __uint_as_float(u.w & 0xffff0000u);
            }
            if (vb0){
                uint4 u = *(const uint4*)(xb + cb0);
                b0 += __uint_as_float(u.x << 16); b1 += __uint_as_float(u.x & 0xffff0000u);
                b2 += __uint_as_float(u.y << 16); b3 += __uint_as_float(u.y & 0xffff0000u);
                b4 += __uint_as_float(u.z << 16); b5 += __uint_as_float(u.z & 0xffff0000u);
                b6 += __uint_as_float(u.w << 16); b7 += __uint_as_float(u.w & 0xffff0000u);
            }
            if (va1){
                uint4 u = *(const uint4*)(xb + ca1);
                a0 += __uint_as_float(u.x << 16); a1 += __uint_as_float(u.x & 0xffff0000u);
                a2 += __uint_as_float(u.y << 16); a3 += __uint_as_float(u.y & 0xffff0000u);
                a4 += __uint_as_float(u.z << 16); a5 += __uint_as_float(u.z & 0xffff0000u);
                a6 += __uint_as_float(u.w << 16); a7 += __uint_as_float(u.w & 0xffff0000u);
            }
            if (vb1){
                uint4 u = *(const uint4*)(xb + cb1);
                b0 += __uint_as_float(u.x << 16); b1 += __uint_as_float(u.x & 0xffff0000u);
                b2 += __uint_as_float(u.y << 16); b3 += __uint_as_float(u.y & 0xffff0000u);
                b4 += __uint_as_float(u.z << 16); b5 += __uint_as_float(u.z & 0xffff0000u);
                b6 += __uint_as_float(u.w << 16); b7 += __uint_as_float(u.w & 0xffff0000u);
            }
            ea += 16; eb += 16;
        }
        // reduce over 8 slots (lane bits 3..5) for both nodes
        a0 += __shfl_xor(a0, 8, 64);  a1 += __shfl_xor(a1, 8, 64);
        a2 += __shfl_xor(a2, 8, 64);  a3 += __shfl_xor(a3, 8, 64);
        a4 += __shfl_xor(a4, 8, 64);  a5 += __shfl_xor(a5, 8, 64);
        a6 += __shfl_xor(a6, 8, 64);  a7 += __shfl_xor(a7, 8, 64);
        b0 += __shfl_xor(b0, 8, 64);  b1 += __shfl_xor(b1, 8, 64);
        b2 += __shfl_xor(b2, 8, 64);  b3 += __shfl_xor(b3, 8, 64);
        b4 += __shfl_xor(b4, 8, 64);  b5 += __shfl_xor(b5, 8, 64);
        b6 += __shfl_xor(b6, 8, 64);  b7 += __shfl_xor(b7, 8, 64);
        a0 += __shfl_xor(a0, 16, 64); a1 += __shfl_xor(a1, 16, 64);
        a2 += __shfl_xor(a2, 16, 64); a3 += __shfl_xor(a3, 16, 64);
        a4 += __shfl_xor(a4, 16, 64); a5 += __shfl_xor(a5, 16, 64);
        a6 += __shfl_xor(a6, 16, 64); a7 += __shfl_xor(a7, 16, 64);
        b0 += __shfl_xor(b0, 16, 64); b1 += __shfl_xor(b1, 16, 64);
        b2 += __shfl_xor(b2, 16, 64); b3 += __shfl_xor(b3, 16, 64);
        b4 += __shfl_xor(b4, 16, 64); b5 += __shfl_xor(b5, 16, 64);
        b6 += __shfl_xor(b6, 16, 64); b7 += __shfl_xor(b7, 16, 64);
        a0 += __shfl_xor(a0, 32, 64); a1 += __shfl_xor(a1, 32, 64);
        a2 += __shfl_xor(a2, 32, 64); a3 += __shfl_xor(a3, 32, 64);
        a4 += __shfl_xor(a4, 32, 64); a5 += __shfl_xor(a5, 32, 64);
        a6 += __shfl_xor(a6, 32, 64); a7 += __shfl_xor(a7, 32, 64);
        b0 += __shfl_xor(b0, 32, 64); b1 += __shfl_xor(b1, 32, 64);
        b2 += __shfl_xor(b2, 32, 64); b3 += __shfl_xor(b3, 32, 64);
        b4 += __shfl_xor(b4, 32, 64); b5 += __shfl_xor(b5, 32, 64);
        b6 += __shfl_xor(b6, 32, 64); b7 += __shfl_xor(b7, 32, 64);
        if (sub == 0){
            float rd = 1.f / fmaxf((float)(e1a - e0a), 1.f);
            ushort8 o;
            o[0] = f2bf(a0*rd); o[1] = f2bf(a1*rd);
            o[2] = f2bf(a2*rd); o[3] = f2bf(a3*rd);
            o[4] = f2bf(a4*rd); o[5] = f2bf(a5*rd);
            o[6] = f2bf(a6*rd); o[7] = f2bf(a7*rd);
            *(ushort8*)((char*)agg + (((size_t)n0) << 7) + (q << 4)) = o;
        } else if (sub == 1){
            float rd = 1.f / fmaxf((float)(e1b - e1a), 1.f);
            ushort8 o;
            o[0] = f2bf(b0*rd); o[1] = f2bf(b1*rd);
            o[2] = f2bf(b2*rd); o[3] = f2bf(b3*rd);
            o[4] = f2bf(b4*rd); o[5] = f2bf(b5*rd);
            o[6] = f2bf(b6*rd); o[7] = f2bf(b7*rd);
            *(ushort8*)((char*)agg + (((size_t)(n0+1)) << 7) + (q << 4)) = o;
        }
    }
}

// ============ MFMA dual-GEMM (all-bf16), TPB=2, wide grid, low-contention BN ============
template<bool AFF>
__global__ __launch_bounds__(256) void k_gemm(
    const unsigned short* __restrict__ agg,   // bf16 mean-agg rows
    const unsigned short* __restrict__ xin,   // bf16 root-branch rows
    unsigned short* __restrict__ hout,        // layer-1 h out (bf16); unused if AFF
    const int* __restrict__ rs, const int* __restrict__ batch,
    const float* __restrict__ Wl, const float* __restrict__ Wr,
    const float* __restrict__ scale,
    const float* __restrict__ bbias, const float* __restrict__ bdelta,
    float* __restrict__ bnpart, float* __restrict__ S)
{
    __shared__ float sS[8*64];     // per-block graph-pool bins (AFF only)
    int t = threadIdx.x;
    int lane = t & 63;
    int jt = t >> 6;
    int g = lane >> 4, r = lane & 15;
    int j = (jt << 4) + r;

    // W fragments: B[k][j], k = ks*32 + 8g + i, scale-folded, trunc hi/lo split
    bf16x8 wlh[2], wll[2], wrh[2], wrl[2];
    #pragma unroll
    for (int ks = 0; ks < 2; ++ks){
        #pragma unroll
        for (int i = 0; i < 8; ++i){
            int k = (ks << 5) + (g << 3) + i;
            float s = AFF ? scale[k] : 1.f;
            float wv = Wl[(k << 6) + j] * s;
            unsigned u = __float_as_uint(wv);
            wlh[ks][i] = (short)(u >> 16);
            float lf = wv - __uint_as_float(u & 0xffff0000u);
            wll[ks][i] = (short)(__float_as_uint(lf) >> 16);
            wv = Wr[(k << 6) + j] * s;
            u = __float_as_uint(wv);
            wrh[ks][i] = (short)(u >> 16);
            lf = wv - __uint_as_float(u & 0xffff0000u);
            wrl[ks][i] = (short)(__float_as_uint(lf) >> 16);
        }
    }

    float bb = bbias[j];
    float bd = AFF ? bdelta[j] : 0.f;

    int gbase = 0, span = 0;
    if (AFF){
        for (int i = t; i < 512; i += 256) sS[i] = 0.f;
        int nfirst = blockIdx.x * (TPB*16);
        int nlast  = min(nfirst + TPB*16 - 1, N_NODES - 1);
        gbase = batch[nfirst];
        span  = batch[nlast] - gbase + 1;
        __syncthreads();
    }

    float bs = 0.f, bq = 0.f;
    int c0 = blockIdx.x * TPB;    // 2 tiles, both valid (3125*2 == NTILES)

    auto LOADT = [&](int tile, bf16x8* A, bf16x8* X, int4& R, int& R5, int4& B){
        size_t rowoff = (((size_t)((tile << 4) + r)) << 6) + (g << 3);
        const bf16x8* pa = (const bf16x8*)(agg + rowoff);
        const bf16x8* px = (const bf16x8*)(xin + rowoff);
        A[0] = pa[0]; A[1] = pa[4];
        X[0] = px[0]; X[1] = px[4];
        if (AFF){
            int nb = (tile << 4) + (g << 2);
            R  = *(const int4*)(rs + nb);
            R5 = rs[nb + 4];
            B  = *(const int4*)(batch + nb);
        }
    };

    auto POOL = [&](int gr, float hv){
        int lg = gr - gbase;
        if (lg < 8) atomicAdd(&sS[(lg << 6) + j], hv);
        else        atomicAdd(&S[(gr << 6) + j], hv);
    };

    auto COMPUTE = [&](int tile, const bf16x8* A, const bf16x8* X,
                       const int4& R, int R5, const int4& B){
        f32x4 accA = {0.f, 0.f, 0.f, 0.f};
        f32x4 accX = {0.f, 0.f, 0.f, 0.f};
        accA = __builtin_amdgcn_mfma_f32_16x16x32_bf16(A[0], wlh[0], accA, 0, 0, 0);
        accA = __builtin_amdgcn_mfma_f32_16x16x32_bf16(A[0], wll[0], accA, 0, 0, 0);
        accA = __builtin_amdgcn_mfma_f32_16x16x32_bf16(A[1], wlh[1], accA, 0, 0, 0);
        accA = __builtin_amdgcn_mfma_f32_16x16x32_bf16(A[1], wll[1], accA, 0, 0, 0);
        accX = __builtin_amdgcn_mfma_f32_16x16x32_bf16(X[0], wrh[0], accX, 0, 0, 0);
        accX = __builtin_amdgcn_mfma_f32_16x16x32_bf16(X[0], wrl[0], accX, 0, 0, 0);
        accX = __builtin_amdgcn_mfma_f32_16x16x32_bf16(X[1], wrh[1], accX, 0, 0, 0);
        accX = __builtin_amdgcn_mfma_f32_16x16x32_bf16(X[1], wrl[1], accX, 0, 0, 0);

        int nb = (tile << 4) + (g << 2);
        if (AFF){
            float hv;
            hv = accA[0] + accX[0] + bb + ((R.y - R.x) > 0 ? bd : 0.f);
            hv = leaky(hv); bs += hv; bq += hv*hv; POOL(B.x, hv);
            hv = accA[1] + accX[1] + bb + ((R.z - R.y) > 0 ? bd : 0.f);
            hv = leaky(hv); bs += hv; bq += hv*hv; POOL(B.y, hv);
            hv = accA[2] + accX[2] + bb + ((R.w - R.z) > 0 ? bd : 0.f);
            hv = leaky(hv); bs += hv; bq += hv*hv; POOL(B.z, hv);
            hv = accA[3] + accX[3] + bb + ((R5 - R.w) > 0 ? bd : 0.f);
            hv = leaky(hv); bs += hv; bq += hv*hv; POOL(B.w, hv);
        } else {
            #pragma unroll
            for (int q2 = 0; q2 < 4; ++q2){
                float hv = leaky(accA[q2] + accX[q2] + bb);
                unsigned short h16 = f2bf(hv);
                float hr = bf2f(h16);
                hout[((size_t)(nb + q2) << 6) + j] = h16;
                bs += hr; bq += hr*hr;
            }
        }
    };

    bf16x8 Aa[2], Xa[2], Ab[2], Xb[2];
    int4 Ra = {0,0,0,0}, Rb = {0,0,0,0}, Ba = {0,0,0,0}, Bb = {0,0,0,0};
    int R5a = 0, R5b = 0;

    LOADT(c0 + 0, Aa, Xa, Ra, R5a, Ba);
    LOADT(c0 + 1, Ab, Xb, Rb, R5b, Bb);
    COMPUTE(c0 + 0, Aa, Xa, Ra, R5a, Ba);
    COMPUTE(c0 + 1, Ab, Xb, Rb, R5b, Bb);

    bs += __shfl_xor(bs, 16, 64); bs += __shfl_xor(bs, 32, 64);
    bq += __shfl_xor(bq, 16, 64); bq += __shfl_xor(bq, 32, 64);
    if (lane < 16){
        float* bp = bnpart + ((blockIdx.x & (BN_SLOTS-1)) * 128);
        atomicAdd(&bp[(jt << 4) + lane], bs);
        atomicAdd(&bp[64 + (jt << 4) + lane], bq);
    }

    if (AFF){
        __syncthreads();
        int sp = min(span, 8);
        for (int i = t; i < (sp << 6); i += 256){
            float v = sS[i];
            if (v != 0.f) atomicAdd(&S[((gbase + (i >> 6)) << 6) + (i & 63)], v);
        }
    }
}

// ============ BN finalize (256 thr): reduce slots; FOLD: fold next-layer biases ============
template<bool FOLD>
__global__ __launch_bounds__(256) void k_bnfin(
    const float* __restrict__ bnpart,
    const float* __restrict__ gamma, const float* __restrict__ beta,
    const float* __restrict__ Wl_nx, const float* __restrict__ Wr_nx,
    const float* __restrict__ bl_nx,
    float* __restrict__ scale, float* __restrict__ shift,
    float* __restrict__ bbias, float* __restrict__ bdelta)
{
    __shared__ float ssh[64];
    int t = threadIdx.x;
    if (t < 64){
        int j = t;
        float s = 0.f, q = 0.f;
        #pragma unroll 8
        for (int i = 0; i < BN_SLOTS; ++i){
            s += bnpart[i*128 + j];
            q += bnpart[i*128 + 64 + j];
        }
        float mu  = s * (1.0f/N_NODES);
        float var = q * (1.0f/N_NODES) - mu*mu;
        float sc  = gamma[j] * rsqrtf(var + EPSV);
        float sh  = beta[j] - mu*sc;
        scale[j] = sc; shift[j] = sh;
        ssh[j] = sh;
    }
    __syncthreads();
    if (FOLD && t < 64){
        int j = t;
        float bbv = bl_nx[j], bdv = 0.f;
        #pragma unroll 8
        for (int k = 0; k < 64; ++k){
            bbv += ssh[k] * Wr_nx[(k << 6) + j];
            bdv += ssh[k] * Wl_nx[(k << 6) + j];
        }
        bbias[j] = bbv; bdelta[j] = bdv;
    }
}

// ============ final MLP (pool finalize fused): one block per graph ============
__global__ __launch_bounds__(256) void k_mlp(
    const float* __restrict__ S, const int* __restrict__ batch,
    const float* __restrict__ scale, const float* __restrict__ shift,
    const float* __restrict__ gf,
    const float* __restrict__ Wm0, const float* __restrict__ bm0,
    const float* __restrict__ Wm1, const float* __restrict__ bm1,
    const float* __restrict__ Wm2, const float* __restrict__ bm2,
    float* __restrict__ out)
{
    __shared__ int seg[2];
    __shared__ float z[128];
    __shared__ float h1[256];
    __shared__ float h2[128];
    int g = blockIdx.x, t = threadIdx.x;
    if (t < 2){
        int target = g + t;
        int lo = 0, hi = N_NODES;
        while (lo < hi){ int mid = (lo+hi)>>1; if (batch[mid] < target) lo = mid+1; else hi = mid; }
        seg[t] = lo;
    }
    __syncthreads();
    float cnt = (float)(seg[1] - seg[0]);
    if (t < 64)
        z[t] = (scale[t]*S[(g<<6)+t] + cnt*shift[t]) / fmaxf(cnt, 1.f);
    else if (t < 128)
        z[t] = gf[g*64 + (t-64)];
    __syncthreads();
    float acc = bm0[t];
    #pragma unroll 8
    for (int k = 0; k < 128; ++k) acc += z[k]*Wm0[k*256 + t];
    h1[t] = leaky(acc);
    __syncthreads();
    if (t < 128){
        float a = bm1[t];
        #pragma unroll 8
        for (int k = 0; k < 256; ++k) a += h1[k]*Wm1[k*128 + t];
        h2[t] = leaky(a);
    }
    __syncthreads();
    if (t < 2){
        float a = bm2[t];
        for (int k = 0; k < 128; ++k) a += h2[k]*Wm2[k*2 + t];
        out[g*2 + t] = a;
    }
}

extern "C" void kernel_launch(void* const* d_in, const int* in_sizes, int n_in,
                              void* d_out, int out_size, void* d_ws, size_t ws_size,
                              hipStream_t stream) {
    const float* x     = (const float*)d_in[0];
    const int*   ei    = (const int*)d_in[1];
    const float* gf    = (const float*)d_in[2];
    const int*   batch = (const int*)d_in[3];
    const float* Wl0 = (const float*)d_in[4];
    const float* bl0 = (const float*)d_in[5];
    const float* Wr0 = (const float*)d_in[6];
    const float* g0  = (const float*)d_in[7];
    const float* b0  = (const float*)d_in[8];
    const float* Wl1 = (const float*)d_in[9];
    const float* bl1 = (const float*)d_in[10];
    const float* Wr1 = (const float*)d_in[11];
    const float* g1  = (const float*)d_in[12];
    const float* b1  = (const float*)d_in[13];
    const float* Wm0 = (const float*)d_in[14];
    const float* bm0 = (const float*)d_in[15];
    const float* Wm1 = (const float*)d_in[16];
    const float* bm1 = (const float*)d_in[17];
    const float* Wm2 = (const float*)d_in[18];
    const float* bm2 = (const float*)d_in[19];

    // ---- workspace ----
    int*   bhist  = (int*)d_ws;                      // [NB]
    int*   boff   = bhist + NB;                      // [NB+1]
    int*   cur    = boff + NB + 1;                   // [NB]
    int*   packed = (int*)d_ws + 2348;               // [E]
    int*   rs     = packed + N_EDGES;                // [N+1] (pad 100004)
    int*   colb   = rs + 100004;                     // [E] byte offsets
    unsigned short* xbf   = (unsigned short*)(colb + N_EDGES);  // [N*64] bf16 x
    unsigned short* h1bf  = xbf + (size_t)N_NODES*FDIM;         // [N*64] bf16 h1
    unsigned short* aggbf = h1bf + (size_t)N_NODES*FDIM;        // [N*64] bf16 agg
    float* bnpartA = (float*)(aggbf + (size_t)N_NODES*FDIM);    // [BN_SLOTS*128]
    float* bnpartB = bnpartA + BN_SLOTS*128;         // [BN_SLOTS*128]
    float* S       = bnpartB + BN_SLOTS*128;         // [128*64]
    float* scale0  = S + N_GRAPHS*FDIM;
    float* shift0  = scale0 + 64;
    float* scale1  = scale0 + 128;
    float* shift1  = scale0 + 192;
    float* bbias   = scale0 + 256;
    float* bdelta  = scale0 + 320;

    const int* srcp = ei;
    const int* dstp = ei + N_EDGES;

    // ---- bucketed CSR build + x conversion (merged; also zeroes bnpartA/B + S) ----
    hipMemsetAsync(bhist, 0, NB*sizeof(int), stream);
    k_prep<<<CVT_BLOCKS + PART_BLOCKS, 256, 0, stream>>>(x, xbf, dstp, bhist, bnpartA);
    k_bscan<<<1, 256, 0, stream>>>(bhist, boff, cur);
    k_part<<<PART_BLOCKS, 256, 0, stream>>>(srcp, dstp, cur, packed);
    k_sort<<<NB, 256, 0, stream>>>(packed, boff, rs, colb);

    // ---- layer 1 ----
    k_agg<<<2048, 256, 0, stream>>>(xbf, rs, colb, aggbf);
    k_gemm<false><<<GEMM_BLOCKS, 256, 0, stream>>>(
        aggbf, xbf, h1bf, rs, batch,
        Wl0, Wr0, nullptr, bl0, nullptr, bnpartA, nullptr);
    k_bnfin<true><<<1, 256, 0, stream>>>(bnpartA, g0, b0, Wl1, Wr1, bl1,
                                         scale0, shift0, bbias, bdelta);

    // ---- layer 2 (h2 never materialized; pooling fused) ----
    k_agg<<<2048, 256, 0, stream>>>(h1bf, rs, colb, aggbf);
    k_gemm<true><<<GEMM_BLOCKS, 256, 0, stream>>>(
        aggbf, h1bf, nullptr, rs, batch,
        Wl1, Wr1, scale0, bbias, bdelta, bnpartB, S);
    k_bnfin<false><<<1, 256, 0, stream>>>(bnpartB, g1, b1, nullptr, nullptr, nullptr,
                                          scale1, shift1, nullptr, nullptr);

    // ---- pooling finalize + MLP ----
    k_mlp<<<N_GRAPHS, 256, 0, stream>>>(S, batch, scale1, shift1, gf,
                                        Wm0, bm0, Wm1, bm1, Wm2, bm2, (float*)d_out);
}